// Round 2
// baseline (3536.502 us; speedup 1.0000x reference)
//
#include <hip/hip_runtime.h>

#define E_N 160000
#define N_N 10000
#define HD  128
#define LAY 16

constexpr int WSTRIDE = 136; // 128 + 8 pad shorts: 272B row stride, 16B aligned

typedef __attribute__((ext_vector_type(8))) short short8;
typedef __attribute__((ext_vector_type(4))) float f32x4;

__device__ __forceinline__ unsigned short f2bf(float f){
  union { float f; unsigned u; } v; v.f = f;
  unsigned r = v.u + 0x7FFFu + ((v.u >> 16) & 1u);   // RNE
  return (unsigned short)(r >> 16);
}
__device__ __forceinline__ float bf2f(unsigned short h){
  union { unsigned u; float f; } v; v.u = ((unsigned)h) << 16; return v.f;
}
__device__ __forceinline__ short8 ld8(const unsigned short* p){
  return *reinterpret_cast<const short8*>(p);
}

// stage a [128 n][128 k] bf16 tile (row-major [n][Kfull], offset kofs) into LDS
template<int NT>
__device__ __forceinline__ void stage_w(unsigned short* lds, const unsigned short* __restrict__ g,
                                        int Kfull, int kofs, int tid){
  #pragma unroll
  for (int i = 0; i < 2048/NT; ++i){
    int cid = i*NT + tid;
    int n = cid >> 4, kc = cid & 15;
    uint4 v = *reinterpret_cast<const uint4*>(g + (size_t)n*Kfull + kofs + kc*8);
    *reinterpret_cast<uint4*>(lds + n*WSTRIDE + kc*8) = v;
  }
}

// ---------------- edge kernel: 128 edges/block, 4 waves x (32 rows x 128 cols) ----------------
__global__ __launch_bounds__(256, 2)
void edge_kernel(float* __restrict__ ef, unsigned short* __restrict__ ef_bf,
                 const unsigned short* __restrict__ nf_bf,
                 const int* __restrict__ src, const int* __restrict__ dst,
                 const unsigned short* __restrict__ wt1, const unsigned short* __restrict__ wt2,
                 const float* __restrict__ b1, const float* __restrict__ b2,
                 const float* __restrict__ g, const float* __restrict__ bt)
{
  __shared__ unsigned short Wbuf[128*WSTRIDE];
  __shared__ unsigned short Htile[128*WSTRIDE];
  const int tid = threadIdx.x, w = tid >> 6, lane = tid & 63, quad = lane >> 4, l16 = lane & 15;
  const int rbase = w*32;
  const long e0 = (long)blockIdx.x * 128;

  // per-lane A row pointers for the 3 concat segments (ef | nf[src] | nf[dst])
  const unsigned short* pA[2][3];
  #pragma unroll
  for (int a=0;a<2;a++){
    long e = e0 + rbase + a*16 + l16;
    pA[a][0] = ef_bf + e*HD;
    pA[a][1] = nf_bf + (long)src[e]*HD;
    pA[a][2] = nf_bf + (long)dst[e]*HD;
  }

  f32x4 acc[16];
  #pragma unroll
  for (int i=0;i<16;i++) acc[i] = (f32x4){0.f,0.f,0.f,0.f};

  // GEMM1: [128,384] @ [384,128], K chunks of 128 == concat segments
  #pragma unroll
  for (int c=0;c<3;c++){
    stage_w<256>(Wbuf, wt1, 384, c*128, tid);
    __syncthreads();
    #pragma unroll
    for (int kk=0;kk<4;kk++){
      const int klocal = kk*32 + quad*8;
      short8 afr0 = ld8(pA[0][c] + klocal);
      short8 afr1 = ld8(pA[1][c] + klocal);
      #pragma unroll
      for (int j=0;j<8;j++){
        short8 bfr = ld8(&Wbuf[(j*16+l16)*WSTRIDE + klocal]);
        acc[j]   = __builtin_amdgcn_mfma_f32_16x16x32_bf16(afr0, bfr, acc[j],   0,0,0);
        acc[8+j] = __builtin_amdgcn_mfma_f32_16x16x32_bf16(afr1, bfr, acc[8+j], 0,0,0);
      }
    }
    __syncthreads();
  }

  // bias + SiLU -> Htile (bf16, A-operand friendly row-major layout)
  float b1v[8];
  #pragma unroll
  for (int j=0;j<8;j++) b1v[j] = b1[j*16+l16];
  #pragma unroll
  for (int a=0;a<2;a++){
    #pragma unroll
    for (int j=0;j<8;j++){
      #pragma unroll
      for (int r=0;r<4;r++){
        float y = acc[a*8+j][r] + b1v[j];
        float h = y / (1.f + __expf(-y));
        Htile[(rbase + a*16 + quad*4 + r)*WSTRIDE + j*16 + l16] = f2bf(h);
      }
    }
  }
  stage_w<256>(Wbuf, wt2, 128, 0, tid);
  __syncthreads();

  // GEMM2: [128,128] @ [128,128]
  #pragma unroll
  for (int i=0;i<16;i++) acc[i] = (f32x4){0.f,0.f,0.f,0.f};
  #pragma unroll
  for (int kk=0;kk<4;kk++){
    const int klocal = kk*32 + quad*8;
    short8 afr0 = ld8(&Htile[(rbase +      l16)*WSTRIDE + klocal]);
    short8 afr1 = ld8(&Htile[(rbase + 16 + l16)*WSTRIDE + klocal]);
    #pragma unroll
    for (int j=0;j<8;j++){
      short8 bfr = ld8(&Wbuf[(j*16+l16)*WSTRIDE + klocal]);
      acc[j]   = __builtin_amdgcn_mfma_f32_16x16x32_bf16(afr0, bfr, acc[j],   0,0,0);
      acc[8+j] = __builtin_amdgcn_mfma_f32_16x16x32_bf16(afr1, bfr, acc[8+j], 0,0,0);
    }
  }

  // epilogue: +b2, LayerNorm, *g+b, residual (fp32), bf16 shadow
  float b2v[8], gv[8], btv[8];
  #pragma unroll
  for (int j=0;j<8;j++){ int col=j*16+l16; b2v[j]=b2[col]; gv[j]=g[col]; btv[j]=bt[col]; }
  #pragma unroll
  for (int a=0;a<2;a++){
    float s1[4]={0,0,0,0}, s2[4]={0,0,0,0};
    #pragma unroll
    for (int j=0;j<8;j++){
      #pragma unroll
      for (int r=0;r<4;r++){
        float y = acc[a*8+j][r] + b2v[j];
        acc[a*8+j][r] = y;
        s1[r]+=y; s2[r]+=y*y;
      }
    }
    #pragma unroll
    for (int m=1;m<16;m<<=1){
      #pragma unroll
      for (int r=0;r<4;r++){ s1[r]+=__shfl_xor(s1[r],m,64); s2[r]+=__shfl_xor(s2[r],m,64); }
    }
    #pragma unroll
    for (int r=0;r<4;r++){
      float mu  = s1[r]*(1.f/HD);
      float var = s2[r]*(1.f/HD) - mu*mu;
      float rstd = rsqrtf(var + 1e-5f);
      long e = e0 + rbase + a*16 + quad*4 + r;
      float* efrow = ef + e*HD;
      unsigned short* efbrow = ef_bf + e*HD;
      #pragma unroll
      for (int j=0;j<8;j++){
        int col = j*16+l16;
        float o  = (acc[a*8+j][r]-mu)*rstd*gv[j] + btv[j];
        float nv = efrow[col] + o;
        efrow[col]  = nv;
        efbrow[col] = f2bf(nv);
      }
    }
  }
}

// ---------------- node kernel: 32 nodes/block, 2 waves, fused CSR gather ----------------
__global__ __launch_bounds__(128)
void node_kernel(float* __restrict__ nf, unsigned short* __restrict__ nf_bf,
                 const unsigned short* __restrict__ ef_bf,
                 const int* __restrict__ ptr, const int* __restrict__ perm,
                 const unsigned short* __restrict__ wt1, const unsigned short* __restrict__ wt2,
                 const float* __restrict__ b1, const float* __restrict__ b2,
                 const float* __restrict__ g, const float* __restrict__ bt)
{
  __shared__ unsigned short Wbuf[128*WSTRIDE];
  __shared__ unsigned short Atile[32*WSTRIDE];
  __shared__ unsigned short Htile[32*WSTRIDE];
  const int tid = threadIdx.x, w = tid >> 6, lane = tid & 63, quad = lane >> 4, l16 = lane & 15;
  const int rbase = w*16;
  const long n0 = (long)blockIdx.x*32;

  // phase 1: segment-sum ef_bf rows into Atile (fp32 accum, bf16 store)
  #pragma unroll 1
  for (int i=0;i<16;i++){
    int node = (int)n0 + w*16 + i;
    float s0=0.f, s1=0.f;
    if (node < N_N){
      int b = ptr[node], e = ptr[node+1];
      for (int t=b; t<e; ++t){
        int ed = perm[t];
        unsigned v = *reinterpret_cast<const unsigned*>(ef_bf + (long)ed*HD + lane*2);
        s0 += bf2f((unsigned short)(v & 0xffffu));
        s1 += bf2f((unsigned short)(v >> 16));
      }
    }
    unsigned pk = (unsigned)f2bf(s0) | ((unsigned)f2bf(s1) << 16);
    *reinterpret_cast<unsigned*>(&Atile[(w*16+i)*WSTRIDE + lane*2]) = pk;
  }

  long nl = n0 + rbase + l16; if (nl > N_N-1) nl = N_N-1;  // clamp for loads
  const unsigned short* pnf = nf_bf + nl*HD;

  f32x4 acc[8];
  #pragma unroll
  for (int i=0;i<8;i++) acc[i] = (f32x4){0.f,0.f,0.f,0.f};

  // GEMM1: [32,256] @ [256,128], chunk0 = Atile (LDS), chunk1 = nf_bf (global)
  #pragma unroll
  for (int c=0;c<2;c++){
    stage_w<128>(Wbuf, wt1, 256, c*128, tid);
    __syncthreads();
    #pragma unroll
    for (int kk=0;kk<4;kk++){
      const int klocal = kk*32 + quad*8;
      short8 afr = (c==0) ? ld8(&Atile[(rbase + l16)*WSTRIDE + klocal])
                          : ld8(pnf + klocal);
      #pragma unroll
      for (int j=0;j<8;j++){
        short8 bfr = ld8(&Wbuf[(j*16+l16)*WSTRIDE + klocal]);
        acc[j] = __builtin_amdgcn_mfma_f32_16x16x32_bf16(afr, bfr, acc[j], 0,0,0);
      }
    }
    __syncthreads();
  }

  float b1v[8];
  #pragma unroll
  for (int j=0;j<8;j++) b1v[j] = b1[j*16+l16];
  #pragma unroll
  for (int j=0;j<8;j++){
    #pragma unroll
    for (int r=0;r<4;r++){
      float y = acc[j][r] + b1v[j];
      float h = y / (1.f + __expf(-y));
      Htile[(rbase + quad*4 + r)*WSTRIDE + j*16 + l16] = f2bf(h);
    }
  }
  stage_w<128>(Wbuf, wt2, 128, 0, tid);
  __syncthreads();

  #pragma unroll
  for (int i=0;i<8;i++) acc[i] = (f32x4){0.f,0.f,0.f,0.f};
  #pragma unroll
  for (int kk=0;kk<4;kk++){
    const int klocal = kk*32 + quad*8;
    short8 afr = ld8(&Htile[(rbase + l16)*WSTRIDE + klocal]);
    #pragma unroll
    for (int j=0;j<8;j++){
      short8 bfr = ld8(&Wbuf[(j*16+l16)*WSTRIDE + klocal]);
      acc[j] = __builtin_amdgcn_mfma_f32_16x16x32_bf16(afr, bfr, acc[j], 0,0,0);
    }
  }

  float b2v[8], gv[8], btv[8];
  #pragma unroll
  for (int j=0;j<8;j++){ int col=j*16+l16; b2v[j]=b2[col]; gv[j]=g[col]; btv[j]=bt[col]; }
  float s1[4]={0,0,0,0}, s2[4]={0,0,0,0};
  #pragma unroll
  for (int j=0;j<8;j++){
    #pragma unroll
    for (int r=0;r<4;r++){
      float y = acc[j][r] + b2v[j];
      acc[j][r] = y; s1[r]+=y; s2[r]+=y*y;
    }
  }
  #pragma unroll
  for (int m=1;m<16;m<<=1){
    #pragma unroll
    for (int r=0;r<4;r++){ s1[r]+=__shfl_xor(s1[r],m,64); s2[r]+=__shfl_xor(s2[r],m,64); }
  }
  #pragma unroll
  for (int r=0;r<4;r++){
    float mu  = s1[r]*(1.f/HD);
    float var = s2[r]*(1.f/HD) - mu*mu;
    float rstd = rsqrtf(var + 1e-5f);
    long nr = n0 + rbase + quad*4 + r;
    if (nr < N_N){
      float* nrow = nf + nr*HD;
      unsigned short* nbrow = nf_bf + nr*HD;
      #pragma unroll
      for (int j=0;j<8;j++){
        int col = j*16+l16;
        float o  = (acc[j][r]-mu)*rstd*gv[j] + btv[j];
        float nv = nrow[col] + o;
        nrow[col]  = nv;
        nbrow[col] = f2bf(nv);
      }
    }
  }
}

// ---------------- utility kernels ----------------
__global__ void cvt_bf16(const float* __restrict__ s, unsigned short* __restrict__ d, long n){
  long i = ((long)blockIdx.x*256 + threadIdx.x)*8;
  if (i >= n) return;
  f32x4 a = *reinterpret_cast<const f32x4*>(s+i);
  f32x4 b = *reinterpret_cast<const f32x4*>(s+i+4);
  short8 v;
  #pragma unroll
  for (int k=0;k<4;k++){ v[k] = (short)f2bf(a[k]); v[4+k] = (short)f2bf(b[k]); }
  *reinterpret_cast<short8*>(d+i) = v;
}

// s: [L][K][128] fp32 -> d: [L][128][K] bf16 (transposed so B-frags read k-contiguous)
__global__ void transpose_w(const float* __restrict__ s, unsigned short* __restrict__ d, int K, long total){
  long idx = (long)blockIdx.x*256 + threadIdx.x;
  if (idx >= total) return;
  int k = (int)(idx % K);
  long t = idx / K;
  int n = (int)(t % 128);
  long l = t / 128;
  d[idx] = f2bf(s[(l*K + k)*128 + n]);
}

// ---------------- CSR build (once per launch) ----------------
__global__ void zero_i32(int* __restrict__ p, int n){
  int i = blockIdx.x*256 + threadIdx.x; if (i < n) p[i] = 0;
}
__global__ void hist_dst(const int* __restrict__ dst, int* __restrict__ cnt, int n){
  int i = blockIdx.x*256 + threadIdx.x; if (i < n) atomicAdd(&cnt[dst[i]], 1);
}
__global__ void scan_cnt(const int* __restrict__ cnt, int* __restrict__ ptr, int n){
  __shared__ int ssum[1024];
  const int tid = threadIdx.x;
  const int PER = (n + 1023) / 1024;
  int base = tid * PER;
  int s = 0;
  for (int i=0;i<PER;i++){ int idx = base+i; s += (idx < n) ? cnt[idx] : 0; }
  ssum[tid] = s; __syncthreads();
  for (int off=1; off<1024; off<<=1){
    int v = (tid >= off) ? ssum[tid-off] : 0;
    __syncthreads();
    ssum[tid] += v;
    __syncthreads();
  }
  int run = (tid == 0) ? 0 : ssum[tid-1];
  for (int i=0;i<PER;i++){
    int idx = base+i;
    if (idx < n){ ptr[idx] = run; run += cnt[idx]; }
  }
  if (tid == 1023) ptr[n] = run;
}
__global__ void fill_perm(const int* __restrict__ dst, int* __restrict__ fill,
                          int* __restrict__ perm, int n){
  int i = blockIdx.x*256 + threadIdx.x;
  if (i < n){ int p = atomicAdd(&fill[dst[i]], 1); perm[p] = i; }
}

extern "C" void kernel_launch(void* const* d_in, const int* in_sizes, int n_in,
                              void* d_out, int out_size, void* d_ws, size_t ws_size,
                              hipStream_t stream) {
  const float* efeat = (const float*)d_in[0];
  const float* nfeat = (const float*)d_in[1];
  const int*   src   = (const int*)d_in[2];
  const int*   dst   = (const int*)d_in[3];
  const float* eW1 = (const float*)d_in[4];
  const float* eb1 = (const float*)d_in[5];
  const float* eW2 = (const float*)d_in[6];
  const float* eb2 = (const float*)d_in[7];
  const float* eg  = (const float*)d_in[8];
  const float* ebt = (const float*)d_in[9];
  const float* nW1 = (const float*)d_in[10];
  const float* nb1 = (const float*)d_in[11];
  const float* nW2 = (const float*)d_in[12];
  const float* nb2 = (const float*)d_in[13];
  const float* ng  = (const float*)d_in[14];
  const float* nbt = (const float*)d_in[15];

  float* ef = (float*)d_out;                  // residual stream lives in d_out
  float* nf = (float*)d_out + (long)E_N*HD;

  char* ws = (char*)d_ws;
  unsigned short* ef_bf = (unsigned short*)ws; ws += (long)E_N*HD*2;
  unsigned short* nf_bf = (unsigned short*)ws; ws += (long)N_N*HD*2;
  unsigned short* wt1e = (unsigned short*)ws;  ws += (long)LAY*128*384*2;
  unsigned short* wt2e = (unsigned short*)ws;  ws += (long)LAY*128*128*2;
  unsigned short* wt1n = (unsigned short*)ws;  ws += (long)LAY*128*256*2;
  unsigned short* wt2n = (unsigned short*)ws;  ws += (long)LAY*128*128*2;
  int* cnt  = (int*)ws; ws += (long)N_N*4;
  int* ptr  = (int*)ws; ws += (long)(N_N+1)*4;
  int* fill = (int*)ws; ws += (long)N_N*4;
  int* perm = (int*)ws; ws += (long)E_N*4;

  hipMemcpyAsync(ef, efeat, (long)E_N*HD*4, hipMemcpyDeviceToDevice, stream);
  hipMemcpyAsync(nf, nfeat, (long)N_N*HD*4, hipMemcpyDeviceToDevice, stream);
  cvt_bf16<<<(E_N*HD/8 + 255)/256, 256, 0, stream>>>(efeat, ef_bf, (long)E_N*HD);
  cvt_bf16<<<(N_N*HD/8 + 255)/256, 256, 0, stream>>>(nfeat, nf_bf, (long)N_N*HD);

  long t1e = (long)LAY*128*384, t2e = (long)LAY*128*128;
  long t1n = (long)LAY*128*256, t2n = (long)LAY*128*128;
  transpose_w<<<(t1e+255)/256, 256, 0, stream>>>(eW1, wt1e, 384, t1e);
  transpose_w<<<(t2e+255)/256, 256, 0, stream>>>(eW2, wt2e, 128, t2e);
  transpose_w<<<(t1n+255)/256, 256, 0, stream>>>(nW1, wt1n, 256, t1n);
  transpose_w<<<(t2n+255)/256, 256, 0, stream>>>(nW2, wt2n, 128, t2n);

  // CSR by dst (once per launch)
  zero_i32<<<(N_N+255)/256, 256, 0, stream>>>(cnt, N_N);
  hist_dst<<<(E_N+255)/256, 256, 0, stream>>>(dst, cnt, E_N);
  scan_cnt<<<1, 1024, 0, stream>>>(cnt, ptr, N_N);
  hipMemcpyAsync(fill, ptr, (long)N_N*4, hipMemcpyDeviceToDevice, stream);
  fill_perm<<<(E_N+255)/256, 256, 0, stream>>>(dst, fill, perm, E_N);

  for (int l = 0; l < LAY; ++l){
    edge_kernel<<<E_N/128, 256, 0, stream>>>(ef, ef_bf, nf_bf, src, dst,
        wt1e + (long)l*128*384, wt2e + (long)l*128*128,
        eb1 + l*HD, eb2 + l*HD, eg + l*HD, ebt + l*HD);
    node_kernel<<<(N_N + 31)/32, 128, 0, stream>>>(nf, nf_bf, ef_bf, ptr, perm,
        wt1n + (long)l*128*256, wt2n + (long)l*128*128,
        nb1 + l*HD, nb2 + l*HD, ng + l*HD, nbt + l*HD);
  }
}

// Round 3
// 1682.169 us; speedup vs baseline: 2.1023x; 2.1023x over previous
//
#include <hip/hip_runtime.h>

#define E_N 160000
#define N_N 10000
#define HD  128
#define LAY 16

constexpr int WSTRIDE = 136; // node kernel: 128 + 8 pad shorts

typedef __attribute__((ext_vector_type(8))) short short8;
typedef __attribute__((ext_vector_type(4))) float f32x4;
typedef __attribute__((ext_vector_type(2))) float f32x2;

__device__ __forceinline__ unsigned short f2bf(float f){
  union { float f; unsigned u; } v; v.f = f;
  unsigned r = v.u + 0x7FFFu + ((v.u >> 16) & 1u);   // RNE
  return (unsigned short)(r >> 16);
}
__device__ __forceinline__ short8 ld8(const unsigned short* p){
  return *reinterpret_cast<const short8*>(p);
}

// ---- padded staging (node kernel) ----
template<int NT>
__device__ __forceinline__ void stage_w(unsigned short* lds, const unsigned short* __restrict__ g,
                                        int Kfull, int kofs, int tid){
  #pragma unroll
  for (int i = 0; i < 2048/NT; ++i){
    int cid = i*NT + tid;
    int n = cid >> 4, kc = cid & 15;
    uint4 v = *reinterpret_cast<const uint4*>(g + (size_t)n*Kfull + kofs + kc*8);
    *reinterpret_cast<uint4*>(lds + n*WSTRIDE + kc*8) = v;
  }
}

// ---- XOR-swizzled staging (edge kernel, no padding): phys_chunk = chunk ^ (row&15) ----
template<int NT>
__device__ __forceinline__ void stage_sw(unsigned short* lds, const unsigned short* __restrict__ g,
                                         int Kfull, int kofs, int tid){
  #pragma unroll
  for (int i = 0; i < 2048/NT; ++i){
    int cid = i*NT + tid;
    int n = cid >> 4, ch = cid & 15;
    int phys = ch ^ (n & 15);
    uint4 v = *reinterpret_cast<const uint4*>(g + (size_t)n*Kfull + kofs + ch*8);
    *reinterpret_cast<uint4*>(lds + n*128 + phys*8) = v;
  }
}

// ---------------- edge kernel: persistent weights in LDS, 512 thr, grid=256 ----------------
__global__ __launch_bounds__(512, 1)
void edge_kernel(float* __restrict__ ef,
                 const unsigned short* __restrict__ nf_bf,
                 const int* __restrict__ src, const int* __restrict__ dst,
                 const unsigned short* __restrict__ wt1, const unsigned short* __restrict__ wt2,
                 const float* __restrict__ b1, const float* __restrict__ b2,
                 const float* __restrict__ g, const float* __restrict__ bt)
{
  __shared__ unsigned short W1a[128*128];  // k 128..256
  __shared__ unsigned short W1b[128*128];  // k 256..384
  __shared__ unsigned short W2 [128*128];
  __shared__ unsigned short Rot[128*128];  // k 0..128 during GEMM1, Htile during GEMM2
  const int tid = threadIdx.x, w = tid >> 6, lane = tid & 63, quad = lane >> 4, l16 = lane & 15;

  stage_sw<512>(W1a, wt1, 384, 128, tid);
  stage_sw<512>(W1b, wt1, 384, 256, tid);
  stage_sw<512>(W2 , wt2, 128, 0,   tid);

  float b1v[8], b2v[8], gv[8], btv[8];
  #pragma unroll
  for (int j=0;j<8;j++){ int col=j*16+l16; b1v[j]=b1[col]; b2v[j]=b2[col]; gv[j]=g[col]; btv[j]=bt[col]; }

  for (int tile = blockIdx.x; tile < E_N/128; tile += gridDim.x){
    const long e = (long)tile*128 + w*16 + l16;
    const float* pef = ef + e*HD;
    const unsigned short* ps = nf_bf + (long)src[e]*HD;
    const unsigned short* pd = nf_bf + (long)dst[e]*HD;

    __syncthreads();                     // prior tile's Rot readers done
    stage_sw<512>(Rot, wt1, 384, 0, tid);

    // prefetch ALL A-fragments for GEMM1
    f32x4 a00[4], a01[4]; short8 a1[4], a2[4];
    #pragma unroll
    for (int kk=0;kk<4;kk++){
      const int kl = kk*32 + quad*8;
      a00[kk] = *reinterpret_cast<const f32x4*>(pef + kl);
      a01[kk] = *reinterpret_cast<const f32x4*>(pef + kl + 4);
      a1[kk]  = ld8(ps + kl);
      a2[kk]  = ld8(pd + kl);
    }
    __syncthreads();

    f32x4 acc[8];
    #pragma unroll
    for (int i=0;i<8;i++) acc[i] = (f32x4){0.f,0.f,0.f,0.f};

    #pragma unroll
    for (int kk=0;kk<4;kk++){
      const int ph = ((kk*4+quad)^l16)*8;
      #pragma unroll
      for (int j=0;j<8;j++)
        acc[j] = __builtin_amdgcn_mfma_f32_16x16x32_bf16(a1[kk], ld8(&W1a[(j*16+l16)*128 + ph]), acc[j], 0,0,0);
    }
    #pragma unroll
    for (int kk=0;kk<4;kk++){
      const int ph = ((kk*4+quad)^l16)*8;
      #pragma unroll
      for (int j=0;j<8;j++)
        acc[j] = __builtin_amdgcn_mfma_f32_16x16x32_bf16(a2[kk], ld8(&W1b[(j*16+l16)*128 + ph]), acc[j], 0,0,0);
    }
    #pragma unroll
    for (int kk=0;kk<4;kk++){
      short8 af;
      #pragma unroll
      for (int i=0;i<4;i++){ af[i] = (short)f2bf(a00[kk][i]); af[4+i] = (short)f2bf(a01[kk][i]); }
      const int ph = ((kk*4+quad)^l16)*8;
      #pragma unroll
      for (int j=0;j<8;j++)
        acc[j] = __builtin_amdgcn_mfma_f32_16x16x32_bf16(af, ld8(&Rot[(j*16+l16)*128 + ph]), acc[j], 0,0,0);
    }
    __syncthreads();                     // Rot reads done, reuse as Htile

    #pragma unroll
    for (int j=0;j<8;j++){
      const int chj = 2*j + (l16>>3);
      #pragma unroll
      for (int r=0;r<4;r++){
        float y = acc[j][r] + b1v[j];
        float h = y / (1.f + __expf(-y));
        int row = w*16 + quad*4 + r;
        Rot[row*128 + ((chj ^ (row&15))*8) + (l16&7)] = f2bf(h);
      }
    }
    __syncthreads();

    #pragma unroll
    for (int i=0;i<8;i++) acc[i] = (f32x4){0.f,0.f,0.f,0.f};
    #pragma unroll
    for (int kk=0;kk<4;kk++){
      const int ph = ((kk*4+quad)^l16)*8;
      short8 af = ld8(&Rot[(w*16+l16)*128 + ph]);
      #pragma unroll
      for (int j=0;j<8;j++)
        acc[j] = __builtin_amdgcn_mfma_f32_16x16x32_bf16(af, ld8(&W2[(j*16+l16)*128 + ph]), acc[j], 0,0,0);
    }

    // +b2, LayerNorm, *g+b, fp32 residual
    float s1[4]={0,0,0,0}, s2[4]={0,0,0,0};
    #pragma unroll
    for (int j=0;j<8;j++){
      #pragma unroll
      for (int r=0;r<4;r++){
        float y = acc[j][r] + b2v[j];
        acc[j][r] = y; s1[r]+=y; s2[r]+=y*y;
      }
    }
    #pragma unroll
    for (int m=1;m<16;m<<=1){
      #pragma unroll
      for (int r=0;r<4;r++){ s1[r]+=__shfl_xor(s1[r],m,64); s2[r]+=__shfl_xor(s2[r],m,64); }
    }
    #pragma unroll
    for (int r=0;r<4;r++){
      float mu  = s1[r]*(1.f/HD);
      float var = s2[r]*(1.f/HD) - mu*mu;
      float rstd = rsqrtf(var + 1e-5f);
      long er = (long)tile*128 + w*16 + quad*4 + r;
      float* erow = ef + er*HD;
      #pragma unroll
      for (int j=0;j<8;j++){
        int col = j*16+l16;
        float o = (acc[j][r]-mu)*rstd*gv[j] + btv[j];
        erow[col] += o;
      }
    }
  }
}

// ---------------- aggregation: one wave per node, float2/lane, 4-deep unroll ----------------
__global__ __launch_bounds__(256)
void agg_kernel(const float* __restrict__ ef, float* __restrict__ agg,
                const int* __restrict__ ptr, const int* __restrict__ perm)
{
  const int w = threadIdx.x >> 6, lane = threadIdx.x & 63;
  const int n = blockIdx.x*4 + w;
  if (n >= N_N) return;
  const int b = ptr[n], e = ptr[n+1];
  float s0 = 0.f, s1 = 0.f;
  int t = b;
  for (; t + 4 <= e; t += 4){
    int i0 = perm[t], i1 = perm[t+1], i2 = perm[t+2], i3 = perm[t+3];
    f32x2 v0 = *reinterpret_cast<const f32x2*>(ef + (long)i0*HD + lane*2);
    f32x2 v1 = *reinterpret_cast<const f32x2*>(ef + (long)i1*HD + lane*2);
    f32x2 v2 = *reinterpret_cast<const f32x2*>(ef + (long)i2*HD + lane*2);
    f32x2 v3 = *reinterpret_cast<const f32x2*>(ef + (long)i3*HD + lane*2);
    s0 += v0[0]+v1[0]+v2[0]+v3[0];
    s1 += v0[1]+v1[1]+v2[1]+v3[1];
  }
  for (; t < e; ++t){
    int i0 = perm[t];
    f32x2 v0 = *reinterpret_cast<const f32x2*>(ef + (long)i0*HD + lane*2);
    s0 += v0[0]; s1 += v0[1];
  }
  *reinterpret_cast<f32x2*>(agg + (long)n*HD + lane*2) = (f32x2){s0, s1};
}

// ---------------- node kernel: 64 nodes/block, 4 waves x (16 rows x 128 cols) ----------------
__global__ __launch_bounds__(256, 2)
void node_kernel(float* __restrict__ nf, unsigned short* __restrict__ nf_bf,
                 const float* __restrict__ agg,
                 const unsigned short* __restrict__ wt1, const unsigned short* __restrict__ wt2,
                 const float* __restrict__ b1, const float* __restrict__ b2,
                 const float* __restrict__ g, const float* __restrict__ bt)
{
  __shared__ unsigned short Wbuf[128*WSTRIDE];
  __shared__ unsigned short Htile[64*WSTRIDE];
  const int tid = threadIdx.x, w = tid >> 6, lane = tid & 63, quad = lane >> 4, l16 = lane & 15;
  const int rbase = w*16;
  const long n0 = (long)blockIdx.x*64;
  long nl = n0 + rbase + l16; if (nl > N_N-1) nl = N_N-1;  // clamp for loads
  const float* pagg = agg + nl*HD;
  const unsigned short* pnf = nf_bf + nl*HD;

  f32x4 acc[8];
  #pragma unroll
  for (int i=0;i<8;i++) acc[i] = (f32x4){0.f,0.f,0.f,0.f};

  // GEMM1: [64,256] @ [256,128], chunk0 = agg (fp32, cvt in-frag), chunk1 = nf_bf
  #pragma unroll
  for (int c=0;c<2;c++){
    stage_w<256>(Wbuf, wt1, 256, c*128, tid);
    __syncthreads();
    #pragma unroll
    for (int kk=0;kk<4;kk++){
      const int klocal = kk*32 + quad*8;
      short8 afr;
      if (c == 0){
        f32x4 u0 = *reinterpret_cast<const f32x4*>(pagg + klocal);
        f32x4 u1 = *reinterpret_cast<const f32x4*>(pagg + klocal + 4);
        #pragma unroll
        for (int i=0;i<4;i++){ afr[i] = (short)f2bf(u0[i]); afr[4+i] = (short)f2bf(u1[i]); }
      } else {
        afr = ld8(pnf + klocal);
      }
      #pragma unroll
      for (int j=0;j<8;j++){
        short8 bfr = ld8(&Wbuf[(j*16+l16)*WSTRIDE + klocal]);
        acc[j] = __builtin_amdgcn_mfma_f32_16x16x32_bf16(afr, bfr, acc[j], 0,0,0);
      }
    }
    __syncthreads();
  }

  float b1v[8];
  #pragma unroll
  for (int j=0;j<8;j++) b1v[j] = b1[j*16+l16];
  #pragma unroll
  for (int j=0;j<8;j++){
    #pragma unroll
    for (int r=0;r<4;r++){
      float y = acc[j][r] + b1v[j];
      float h = y / (1.f + __expf(-y));
      Htile[(rbase + quad*4 + r)*WSTRIDE + j*16 + l16] = f2bf(h);
    }
  }
  stage_w<256>(Wbuf, wt2, 128, 0, tid);
  __syncthreads();

  #pragma unroll
  for (int i=0;i<8;i++) acc[i] = (f32x4){0.f,0.f,0.f,0.f};
  #pragma unroll
  for (int kk=0;kk<4;kk++){
    const int klocal = kk*32 + quad*8;
    short8 afr = ld8(&Htile[(rbase + l16)*WSTRIDE + klocal]);
    #pragma unroll
    for (int j=0;j<8;j++){
      short8 bfr = ld8(&Wbuf[(j*16+l16)*WSTRIDE + klocal]);
      acc[j] = __builtin_amdgcn_mfma_f32_16x16x32_bf16(afr, bfr, acc[j], 0,0,0);
    }
  }

  float b2v[8], gv[8], btv[8];
  #pragma unroll
  for (int j=0;j<8;j++){ int col=j*16+l16; b2v[j]=b2[col]; gv[j]=g[col]; btv[j]=bt[col]; }
  float s1[4]={0,0,0,0}, s2[4]={0,0,0,0};
  #pragma unroll
  for (int j=0;j<8;j++){
    #pragma unroll
    for (int r=0;r<4;r++){
      float y = acc[j][r] + b2v[j];
      acc[j][r] = y; s1[r]+=y; s2[r]+=y*y;
    }
  }
  #pragma unroll
  for (int m=1;m<16;m<<=1){
    #pragma unroll
    for (int r=0;r<4;r++){ s1[r]+=__shfl_xor(s1[r],m,64); s2[r]+=__shfl_xor(s2[r],m,64); }
  }
  #pragma unroll
  for (int r=0;r<4;r++){
    float mu  = s1[r]*(1.f/HD);
    float var = s2[r]*(1.f/HD) - mu*mu;
    float rstd = rsqrtf(var + 1e-5f);
    long nr = n0 + rbase + quad*4 + r;
    if (nr < N_N){
      float* nrow = nf + nr*HD;
      unsigned short* nbrow = nf_bf + nr*HD;
      #pragma unroll
      for (int j=0;j<8;j++){
        int col = j*16+l16;
        float o  = (acc[j][r]-mu)*rstd*gv[j] + btv[j];
        float nv = nrow[col] + o;
        nrow[col]  = nv;
        nbrow[col] = f2bf(nv);
      }
    }
  }
}

// ---------------- utility kernels ----------------
__global__ void cvt_bf16(const float* __restrict__ s, unsigned short* __restrict__ d, long n){
  long i = ((long)blockIdx.x*256 + threadIdx.x)*8;
  if (i >= n) return;
  f32x4 a = *reinterpret_cast<const f32x4*>(s+i);
  f32x4 b = *reinterpret_cast<const f32x4*>(s+i+4);
  short8 v;
  #pragma unroll
  for (int k=0;k<4;k++){ v[k] = (short)f2bf(a[k]); v[4+k] = (short)f2bf(b[k]); }
  *reinterpret_cast<short8*>(d+i) = v;
}

// s: [L][K][128] fp32 -> d: [L][128][K] bf16
__global__ void transpose_w(const float* __restrict__ s, unsigned short* __restrict__ d, int K, long total){
  long idx = (long)blockIdx.x*256 + threadIdx.x;
  if (idx >= total) return;
  int k = (int)(idx % K);
  long t = idx / K;
  int n = (int)(t % 128);
  long l = t / 128;
  d[idx] = f2bf(s[(l*K + k)*128 + n]);
}

// ---------------- CSR build (once per launch) ----------------
__global__ void zero_i32(int* __restrict__ p, int n){
  int i = blockIdx.x*256 + threadIdx.x; if (i < n) p[i] = 0;
}
__global__ void hist_dst(const int* __restrict__ dst, int* __restrict__ cnt, int n){
  int i = blockIdx.x*256 + threadIdx.x; if (i < n) atomicAdd(&cnt[dst[i]], 1);
}
__global__ void scan_cnt(const int* __restrict__ cnt, int* __restrict__ ptr, int n){
  __shared__ int ssum[1024];
  const int tid = threadIdx.x;
  const int PER = (n + 1023) / 1024;
  int base = tid * PER;
  int s = 0;
  for (int i=0;i<PER;i++){ int idx = base+i; s += (idx < n) ? cnt[idx] : 0; }
  ssum[tid] = s; __syncthreads();
  for (int off=1; off<1024; off<<=1){
    int v = (tid >= off) ? ssum[tid-off] : 0;
    __syncthreads();
    ssum[tid] += v;
    __syncthreads();
  }
  int run = (tid == 0) ? 0 : ssum[tid-1];
  for (int i=0;i<PER;i++){
    int idx = base+i;
    if (idx < n){ ptr[idx] = run; run += cnt[idx]; }
  }
  if (tid == 1023) ptr[n] = run;
}
__global__ void fill_perm(const int* __restrict__ dst, int* __restrict__ fill,
                          int* __restrict__ perm, int n){
  int i = blockIdx.x*256 + threadIdx.x;
  if (i < n){ int p = atomicAdd(&fill[dst[i]], 1); perm[p] = i; }
}

extern "C" void kernel_launch(void* const* d_in, const int* in_sizes, int n_in,
                              void* d_out, int out_size, void* d_ws, size_t ws_size,
                              hipStream_t stream) {
  const float* efeat = (const float*)d_in[0];
  const float* nfeat = (const float*)d_in[1];
  const int*   src   = (const int*)d_in[2];
  const int*   dst   = (const int*)d_in[3];
  const float* eW1 = (const float*)d_in[4];
  const float* eb1 = (const float*)d_in[5];
  const float* eW2 = (const float*)d_in[6];
  const float* eb2 = (const float*)d_in[7];
  const float* eg  = (const float*)d_in[8];
  const float* ebt = (const float*)d_in[9];
  const float* nW1 = (const float*)d_in[10];
  const float* nb1 = (const float*)d_in[11];
  const float* nW2 = (const float*)d_in[12];
  const float* nb2 = (const float*)d_in[13];
  const float* ng  = (const float*)d_in[14];
  const float* nbt = (const float*)d_in[15];

  float* ef = (float*)d_out;                  // fp32 residual streams live in d_out
  float* nf = (float*)d_out + (long)E_N*HD;

  char* ws = (char*)d_ws;
  float* agg = (float*)ws;                     ws += (long)N_N*HD*4;
  unsigned short* nf_bf = (unsigned short*)ws; ws += (long)N_N*HD*2;
  unsigned short* wt1e = (unsigned short*)ws;  ws += (long)LAY*128*384*2;
  unsigned short* wt2e = (unsigned short*)ws;  ws += (long)LAY*128*128*2;
  unsigned short* wt1n = (unsigned short*)ws;  ws += (long)LAY*128*256*2;
  unsigned short* wt2n = (unsigned short*)ws;  ws += (long)LAY*128*128*2;
  int* cnt  = (int*)ws; ws += (long)N_N*4;
  int* ptr  = (int*)ws; ws += (long)(N_N+1)*4;
  int* fill = (int*)ws; ws += (long)N_N*4;
  int* perm = (int*)ws; ws += (long)E_N*4;

  hipMemcpyAsync(ef, efeat, (long)E_N*HD*4, hipMemcpyDeviceToDevice, stream);
  hipMemcpyAsync(nf, nfeat, (long)N_N*HD*4, hipMemcpyDeviceToDevice, stream);
  cvt_bf16<<<(N_N*HD/8 + 255)/256, 256, 0, stream>>>(nfeat, nf_bf, (long)N_N*HD);

  long t1e = (long)LAY*128*384, t2e = (long)LAY*128*128;
  long t1n = (long)LAY*128*256, t2n = (long)LAY*128*128;
  transpose_w<<<(t1e+255)/256, 256, 0, stream>>>(eW1, wt1e, 384, t1e);
  transpose_w<<<(t2e+255)/256, 256, 0, stream>>>(eW2, wt2e, 128, t2e);
  transpose_w<<<(t1n+255)/256, 256, 0, stream>>>(nW1, wt1n, 256, t1n);
  transpose_w<<<(t2n+255)/256, 256, 0, stream>>>(nW2, wt2n, 128, t2n);

  // CSR by dst (once per launch)
  zero_i32<<<(N_N+255)/256, 256, 0, stream>>>(cnt, N_N);
  hist_dst<<<(E_N+255)/256, 256, 0, stream>>>(dst, cnt, E_N);
  scan_cnt<<<1, 1024, 0, stream>>>(cnt, ptr, N_N);
  hipMemcpyAsync(fill, ptr, (long)N_N*4, hipMemcpyDeviceToDevice, stream);
  fill_perm<<<(E_N+255)/256, 256, 0, stream>>>(dst, fill, perm, E_N);

  for (int l = 0; l < LAY; ++l){
    edge_kernel<<<256, 512, 0, stream>>>(ef, nf_bf, src, dst,
        wt1e + (long)l*128*384, wt2e + (long)l*128*128,
        eb1 + l*HD, eb2 + l*HD, eg + l*HD, ebt + l*HD);
    agg_kernel<<<N_N/4, 256, 0, stream>>>(ef, agg, ptr, perm);
    node_kernel<<<(N_N + 63)/64, 256, 0, stream>>>(nf, nf_bf, agg,
        wt1n + (long)l*128*256, wt2n + (long)l*128*128,
        nb1 + l*HD, nb2 + l*HD, ng + l*HD, nbt + l*HD);
  }
}